// Round 1
// 217.752 us; speedup vs baseline: 1.0099x; 1.0099x over previous
//
#include <hip/hip_runtime.h>

// MaskedAttentionLayer B=4,S=2048,E=1024,H=16,HD=64; fp32 io, bf16 MFMA.
// R7: qkv_gemm rewritten as 256x256 tile, BK=64, 512 thr / 8 waves,
// dispersed-quadrant wave mapping, 4-phase counted-vmcnt pipeline
// (T2 XOR-swizzle + T3/T4 counted vmcnt(4) + T5 setprio). 2 LDS buffers
// (128 KiB), one half-tile staged per phase, vmcnt never drains to 0 in
// the main loop (peeled last tile only). cvt_all + flash_attn unchanged.

typedef __bf16 bf16x8 __attribute__((ext_vector_type(8)));
typedef __bf16 bf16x4 __attribute__((ext_vector_type(4)));
typedef float f32x4 __attribute__((ext_vector_type(4)));
typedef unsigned short us8 __attribute__((ext_vector_type(8)));
typedef unsigned short us4 __attribute__((ext_vector_type(4)));

#define Bb 4
#define Ss 2048
#define Ee 1024
#define Hh 16
#define HD 64

#if __has_builtin(__builtin_amdgcn_exp2f)
#define EXP2(x) __builtin_amdgcn_exp2f(x)
#else
#define EXP2(x) exp2f(x)
#endif

__device__ __forceinline__ unsigned short f2bf(float f) {
  union { float f; unsigned u; } v; v.f = f;
  unsigned u = v.u;
  u += 0x7fffu + ((u >> 16) & 1u);   // RNE
  return (unsigned short)(u >> 16);
}

__device__ __forceinline__ void gl_lds16(const void* g, void* l) {
  __builtin_amdgcn_global_load_lds((const __attribute__((address_space(1))) void*)g,
                                   (__attribute__((address_space(3))) void*)l, 16, 0, 0);
}

// one kernel for all fp32->bf16 converts (x, Wq, Wk, Wv)
__global__ __launch_bounds__(256) void cvt_all(const float* __restrict__ x,
                                               const float* __restrict__ wq,
                                               const float* __restrict__ wk,
                                               const float* __restrict__ wv,
                                               unsigned short* __restrict__ xb,
                                               unsigned short* __restrict__ wb) {
  int i = blockIdx.x * 256 + threadIdx.x;   // float4 index, total 2883584
  const float* src; unsigned short* dst; int idx;
  if (i < 2097152)      { src = x;  dst = xb;                idx = i; }
  else if (i < 2359296) { src = wq; dst = wb;                idx = i - 2097152; }
  else if (i < 2621440) { src = wk; dst = wb + 1048576;      idx = i - 2359296; }
  else                  { src = wv; dst = wb + 2 * 1048576;  idx = i - 2621440; }
  float4 f = ((const float4*)src)[idx];
  us4 o = { f2bf(f.x), f2bf(f.y), f2bf(f.z), f2bf(f.w) };
  ((us4*)dst)[idx] = o;
}

// C[m,n] = sum_e X[m,e] W[n,e] + bias[n].
// 256x256 tile, BK=64, 512 threads = 8 waves. Dispersed-quadrant mapping:
// wave w = (wr=w>>2, wc=w&3); in each C-quadrant (qa,qb) the wave owns the
// 64x32 subtile rows qa*128+wr*64.., cols qb*128+wc*32.. . Phase (qa,qb)
// therefore touches ONLY A-half qa and B-half qb of the K-tile -> half-tile
// granular pipeline with 2 LDS buffers.
// LDS per buffer: A [256][64] @0, B [256][64] @16384 elems; XOR chunk swizzle
// (chunk ^= row&7) applied via pre-swizzled global source + swizzled ds_read.
// Per tile kt (buf=kt&1): 4 phases, each: vmcnt(4); barrier; ds_reads;
// stage one half-tile of kt+1 (order A0,B0,B1,A1); barrier; setprio+16 MFMA.
// z=0 (Q): [b,h,s,d] scaled by 0.125*log2e.  z=1 (K): [b,h,s,d].  z=2 (V): [b,h,d,s].
__global__ __launch_bounds__(512, 2) void qkv_gemm(const unsigned short* __restrict__ xb,
                                                   const unsigned short* __restrict__ wb_all,
                                                   const float* __restrict__ bq,
                                                   const float* __restrict__ bk,
                                                   const float* __restrict__ bv,
                                                   unsigned short* __restrict__ qkv) {
  const int z = blockIdx.z;
  const unsigned short* wb = wb_all + (size_t)z * (Ee * Ee);
  const float* bias = (z == 0) ? bq : (z == 1) ? bk : bv;
  unsigned short* outb = qkv + (size_t)z * (Bb * Ss * Ee);
  const float osc = (z == 0) ? 0.180336880f : 1.0f;   // 0.125 * log2(e)

  __shared__ unsigned short SMEM[65536];   // 128 KiB: 2 x (A 16384 + B 16384 elems)

  const int t = threadIdx.x;
  const int wave = t >> 6, lane = t & 63, quad = lane >> 4, ln = lane & 15;
  const int wr = wave >> 2, wc = wave & 3;
  const int m0 = blockIdx.x * 256, n0 = blockIdx.y * 256;

  // ---- staging addresses: thread t loads row r8=t>>3 (+64 per second load),
  // global chunk cs = (t&7) ^ (r8&7) -> LDS linear dest t*8 (both-sides swizzle).
  const int r8 = t >> 3;
  const int cs = ((t & 7) ^ (r8 & 7)) * 8;
  const int t8 = t * 8;
  const unsigned short* gA0 = xb + (size_t)(m0 + r8) * Ee + cs;        // A rows 0..127
  const unsigned short* gA1 = gA0 + 128 * Ee;                          // A rows 128..255
  const unsigned short* gB0 = wb + (size_t)(n0 + r8) * Ee + cs;        // B rows 0..127
  const unsigned short* gB1 = gB0 + 128 * Ee;                          // B rows 128..255

  // ---- ds_read element offsets (qa/qb==1 adds +8192 = 128 rows)
  int aoff0[4][2], boff0[2][2];
#pragma unroll
  for (int i = 0; i < 4; ++i)
#pragma unroll
    for (int kk = 0; kk < 2; ++kk)
      aoff0[i][kk] = (wr * 64 + i * 16 + ln) * 64 + (((kk * 4 + quad) ^ (ln & 7)) * 8);
#pragma unroll
  for (int j = 0; j < 2; ++j)
#pragma unroll
    for (int kk = 0; kk < 2; ++kk)
      boff0[j][kk] = 16384 + (wc * 32 + j * 16 + ln) * 64 + (((kk * 4 + quad) ^ (ln & 7)) * 8);

  f32x4 acc[2][2][4][2] = {};

  // ---- prologue: stage tile 0 into buf0, half order A0,B0,B1,A1 (vmcnt order!)
  gl_lds16(gA0,           &SMEM[t8]);
  gl_lds16(gA0 + 64 * Ee, &SMEM[t8 + 4096]);
  gl_lds16(gB0,           &SMEM[16384 + t8]);
  gl_lds16(gB0 + 64 * Ee, &SMEM[16384 + t8 + 4096]);
  gl_lds16(gB1,           &SMEM[24576 + t8]);
  gl_lds16(gB1 + 64 * Ee, &SMEM[24576 + t8 + 4096]);
  gl_lds16(gA1,           &SMEM[8192 + t8]);
  gl_lds16(gA1 + 64 * Ee, &SMEM[8192 + t8 + 4096]);

#pragma unroll 1
  for (int kt = 0; kt < 15; ++kt) {
    const int cbuf = (kt & 1) << 15;        // compute buffer (elems)
    const int sbuf = cbuf ^ 32768;          // stage buffer for tile kt+1
    const int co = (kt + 1) * 64;           // next tile's K-column offset

    bf16x8 af[4][2], bf0[2][2], bf1[2][2];

    // ---- phase 0: C(qa0,qb0); reads A-half0 + B-half0; stages A0(kt+1)
    asm volatile("s_waitcnt vmcnt(4)" ::: "memory");
    asm volatile("s_barrier" ::: "memory");
#pragma unroll
    for (int i = 0; i < 4; ++i)
#pragma unroll
      for (int kk = 0; kk < 2; ++kk)
        af[i][kk] = *(const bf16x8*)&SMEM[cbuf + aoff0[i][kk]];
#pragma unroll
    for (int j = 0; j < 2; ++j)
#pragma unroll
      for (int kk = 0; kk < 2; ++kk)
        bf0[j][kk] = *(const bf16x8*)&SMEM[cbuf + boff0[j][kk]];
    gl_lds16(gA0 + co,           &SMEM[sbuf + t8]);
    gl_lds16(gA0 + co + 64 * Ee, &SMEM[sbuf + t8 + 4096]);
    asm volatile("s_barrier" ::: "memory");
    __builtin_amdgcn_s_setprio(1);
#pragma unroll
    for (int i = 0; i < 4; ++i)
#pragma unroll
      for (int j = 0; j < 2; ++j)
#pragma unroll
        for (int kk = 0; kk < 2; ++kk)
          acc[0][0][i][j] = __builtin_amdgcn_mfma_f32_16x16x32_bf16(af[i][kk], bf0[j][kk], acc[0][0][i][j], 0, 0, 0);
    __builtin_amdgcn_s_setprio(0);

    // ---- phase 1: C(qa0,qb1); reads B-half1; stages B0(kt+1)
    asm volatile("s_waitcnt vmcnt(4)" ::: "memory");
    asm volatile("s_barrier" ::: "memory");
#pragma unroll
    for (int j = 0; j < 2; ++j)
#pragma unroll
      for (int kk = 0; kk < 2; ++kk)
        bf1[j][kk] = *(const bf16x8*)&SMEM[cbuf + boff0[j][kk] + 8192];
    gl_lds16(gB0 + co,           &SMEM[sbuf + 16384 + t8]);
    gl_lds16(gB0 + co + 64 * Ee, &SMEM[sbuf + 16384 + t8 + 4096]);
    asm volatile("s_barrier" ::: "memory");
    __builtin_amdgcn_s_setprio(1);
#pragma unroll
    for (int i = 0; i < 4; ++i)
#pragma unroll
      for (int j = 0; j < 2; ++j)
#pragma unroll
        for (int kk = 0; kk < 2; ++kk)
          acc[0][1][i][j] = __builtin_amdgcn_mfma_f32_16x16x32_bf16(af[i][kk], bf1[j][kk], acc[0][1][i][j], 0, 0, 0);
    __builtin_amdgcn_s_setprio(0);

    // ---- phase 2: C(qa1,qb0); reads A-half1; stages B1(kt+1)
    asm volatile("s_waitcnt vmcnt(4)" ::: "memory");
    asm volatile("s_barrier" ::: "memory");
#pragma unroll
    for (int i = 0; i < 4; ++i)
#pragma unroll
      for (int kk = 0; kk < 2; ++kk)
        af[i][kk] = *(const bf16x8*)&SMEM[cbuf + aoff0[i][kk] + 8192];
    gl_lds16(gB1 + co,           &SMEM[sbuf + 24576 + t8]);
    gl_lds16(gB1 + co + 64 * Ee, &SMEM[sbuf + 24576 + t8 + 4096]);
    asm volatile("s_barrier" ::: "memory");
    __builtin_amdgcn_s_setprio(1);
#pragma unroll
    for (int i = 0; i < 4; ++i)
#pragma unroll
      for (int j = 0; j < 2; ++j)
#pragma unroll
        for (int kk = 0; kk < 2; ++kk)
          acc[1][0][i][j] = __builtin_amdgcn_mfma_f32_16x16x32_bf16(af[i][kk], bf0[j][kk], acc[1][0][i][j], 0, 0, 0);
    __builtin_amdgcn_s_setprio(0);

    // ---- phase 3: C(qa1,qb1); no reads; stages A1(kt+1)
    asm volatile("s_barrier" ::: "memory");
    gl_lds16(gA1 + co,           &SMEM[sbuf + 8192 + t8]);
    gl_lds16(gA1 + co + 64 * Ee, &SMEM[sbuf + 8192 + t8 + 4096]);
    asm volatile("s_barrier" ::: "memory");
    __builtin_amdgcn_s_setprio(1);
#pragma unroll
    for (int i = 0; i < 4; ++i)
#pragma unroll
      for (int j = 0; j < 2; ++j)
#pragma unroll
        for (int kk = 0; kk < 2; ++kk)
          acc[1][1][i][j] = __builtin_amdgcn_mfma_f32_16x16x32_bf16(af[i][kk], bf1[j][kk], acc[1][1][i][j], 0, 0, 0);
    __builtin_amdgcn_s_setprio(0);
  }

  // ---- peeled tile 15 (buf1): only place vmcnt drains to 0
  {
    const int cbuf = 32768;
    bf16x8 af[4][2], bf0[2][2], bf1[2][2];
    asm volatile("s_waitcnt vmcnt(0)" ::: "memory");
    asm volatile("s_barrier" ::: "memory");
#pragma unroll
    for (int i = 0; i < 4; ++i)
#pragma unroll
      for (int kk = 0; kk < 2; ++kk)
        af[i][kk] = *(const bf16x8*)&SMEM[cbuf + aoff0[i][kk]];
#pragma unroll
    for (int j = 0; j < 2; ++j)
#pragma unroll
      for (int kk = 0; kk < 2; ++kk) {
        bf0[j][kk] = *(const bf16x8*)&SMEM[cbuf + boff0[j][kk]];
        bf1[j][kk] = *(const bf16x8*)&SMEM[cbuf + boff0[j][kk] + 8192];
      }
#pragma unroll
    for (int i = 0; i < 4; ++i)
#pragma unroll
      for (int j = 0; j < 2; ++j)
#pragma unroll
        for (int kk = 0; kk < 2; ++kk) {
          acc[0][0][i][j] = __builtin_amdgcn_mfma_f32_16x16x32_bf16(af[i][kk], bf0[j][kk], acc[0][0][i][j], 0, 0, 0);
          acc[0][1][i][j] = __builtin_amdgcn_mfma_f32_16x16x32_bf16(af[i][kk], bf1[j][kk], acc[0][1][i][j], 0, 0, 0);
        }
#pragma unroll
    for (int i = 0; i < 4; ++i)
#pragma unroll
      for (int kk = 0; kk < 2; ++kk)
        af[i][kk] = *(const bf16x8*)&SMEM[cbuf + aoff0[i][kk] + 8192];
#pragma unroll
    for (int i = 0; i < 4; ++i)
#pragma unroll
      for (int j = 0; j < 2; ++j)
#pragma unroll
        for (int kk = 0; kk < 2; ++kk) {
          acc[1][0][i][j] = __builtin_amdgcn_mfma_f32_16x16x32_bf16(af[i][kk], bf0[j][kk], acc[1][0][i][j], 0, 0, 0);
          acc[1][1][i][j] = __builtin_amdgcn_mfma_f32_16x16x32_bf16(af[i][kk], bf1[j][kk], acc[1][1][i][j], 0, 0, 0);
        }
  }

  // ---- epilogue
  float biasj[2][2];
#pragma unroll
  for (int qb = 0; qb < 2; ++qb)
#pragma unroll
    for (int j = 0; j < 2; ++j)
      biasj[qb][j] = bias[n0 + qb * 128 + wc * 32 + j * 16 + ln];

  if (z != 2) {
#pragma unroll
    for (int qa = 0; qa < 2; ++qa)
#pragma unroll
      for (int qb = 0; qb < 2; ++qb)
#pragma unroll
        for (int i = 0; i < 4; ++i)
#pragma unroll
          for (int j = 0; j < 2; ++j)
#pragma unroll
            for (int r = 0; r < 4; ++r) {
              int m = m0 + qa * 128 + wr * 64 + i * 16 + quad * 4 + r;
              int n = n0 + qb * 128 + wc * 32 + j * 16 + ln;
              int b_ = m >> 11, s = m & 2047;
              int h = n >> 6, d = n & 63;
              outb[(((size_t)b_ * Hh + h) * Ss + s) * HD + d] =
                  f2bf((acc[qa][qb][i][j][r] + biasj[qb][j]) * osc);
            }
  } else {
    // V: transpose to [b,h,d,s] through LDS, one 128-row m-half at a time
    for (int qa = 0; qa < 2; ++qa) {
      __syncthreads();
#pragma unroll
      for (int qb = 0; qb < 2; ++qb)
#pragma unroll
        for (int i = 0; i < 4; ++i)
#pragma unroll
          for (int j = 0; j < 2; ++j)
#pragma unroll
            for (int r = 0; r < 4; ++r) {
              int nc = qb * 128 + wc * 32 + j * 16 + ln;
              int mr = wr * 64 + i * 16 + quad * 4 + r;
              SMEM[nc * 136 + mr] = f2bf(acc[qa][qb][i][j][r] + biasj[qb][j]);
            }
      __syncthreads();
      int nr = t >> 1, mh = t & 1;
      int n = n0 + nr, h = n >> 6, d = n & 63;
      int b_ = m0 >> 11;
      int s0 = (m0 & 2047) + qa * 128 + mh * 64;
#pragma unroll
      for (int q = 0; q < 8; ++q) {
        us8 vdat = *(const us8*)&SMEM[nr * 136 + mh * 64 + q * 8];
        *(us8*)&outb[(((size_t)b_ * Hh + h) * HD + d) * Ss + s0 + q * 8] = vdat;
      }
    }
  }
}

// Flash attention, causal, S^T = K Q^T, max-free exp2 softmax.
// grid = 512 (64 bh x 8 pairs); block owns q-tile of 128 rows as two 64-row
// subtiles (u=0,1); each wave: 16 rows per subtile -> 36 MFMA per barrier pair.
__global__ __launch_bounds__(256) void flash_attn(const unsigned short* __restrict__ qkv,
                                                  float* __restrict__ out) {
  const int id = blockIdx.x;
  const int bh = id & 63;
  const int p = id >> 6;            // 0..7
  const int b_ = bh >> 4, h = bh & 15;

  const unsigned short* qb  = qkv + (size_t)bh * (Ss * HD);
  const unsigned short* kb  = qkv + (size_t)(64 + bh) * (Ss * HD);
  const unsigned short* vtb = qkv + (size_t)(128 + bh) * (Ss * HD);  // [d][s]

  __shared__ __bf16 Ks[4096];            // logical [kcol][d], slot r*8+(c8^(r&7))
  __shared__ __bf16 Vt[4096];            // logical [d][kk], same swizzle
  __shared__ __bf16 Ps[4][2][16][72];    // per (wave, subtile) P [qrow][kk]

  const int t = threadIdx.x;
  const int wave = t >> 6, lane = t & 63, quad = lane >> 4, ln = lane & 15;

  const int r0 = t >> 3;
  const int c0 = ((t & 7) ^ (r0 & 7)) * 8;
  const int koff0 = r0 * HD + c0;
  const int koff1 = koff0 + 32 * HD;
  const int voff0 = r0 * Ss + c0;
  const int voff1 = voff0 + 32 * Ss;
  __bf16* Kl0 = &Ks[t * 8];  __bf16* Kl1 = &Ks[2048 + t * 8];
  __bf16* Vl0 = &Vt[t * 8];  __bf16* Vl1 = &Vt[2048 + t * 8];

  int kslot[4][2];
#pragma unroll
  for (int g = 0; g < 4; ++g)
#pragma unroll
    for (int ks = 0; ks < 2; ++ks)
      kslot[g][ks] = ((g * 16 + ln) * 8 + ((ks * 4 + quad) ^ (ln & 7))) * 8;

  bf16x8 onef;
#pragma unroll
  for (int j = 0; j < 8; ++j) onef[j] = (__bf16)1.0f;

  const int qtps[2] = { 15 - p, p };

  for (int ph = 0; ph < 2; ++ph) {
    const int qtp = qtps[ph];
    const int q0 = qtp * 128;

    bf16x8 qf[2][2];
#pragma unroll
    for (int u = 0; u < 2; ++u)
#pragma unroll
      for (int ks = 0; ks < 2; ++ks)
        qf[u][ks] = *(const bf16x8*)(qb + (size_t)(q0 + u * 64 + wave * 16 + ln) * HD +
                                     ks * 32 + quad * 8);

    f32x4 o[2][4] = {};
    f32x4 l4[2] = {};
    const int ktmax = 2 * qtp + 1;

    for (int kt = 0; kt <= ktmax; ++kt) {
      const unsigned short* kbt = kb + kt * (64 * HD);
      const unsigned short* vbt = vtb + kt * 64;
      __syncthreads();
      gl_lds16(kbt + koff0, Kl0);
      gl_lds16(kbt + koff1, Kl1);
      gl_lds16(vbt + voff0, Vl0);
      gl_lds16(vbt + voff1, Vl1);
      __syncthreads();

#pragma unroll
      for (int u = 0; u < 2; ++u) {
        if (u == 0 && kt == ktmax) continue;   // subtile 0 fully masked on last kt
        const int qrow = q0 + u * 64 + wave * 16 + ln;

        // S^T = K Q^T
        f32x4 s_acc[4] = {};
#pragma unroll
        for (int g = 0; g < 4; ++g)
#pragma unroll
          for (int ks = 0; ks < 2; ++ks) {
            bf16x8 kf = *(const bf16x8*)&Ks[kslot[g][ks]];
            s_acc[g] = __builtin_amdgcn_mfma_f32_16x16x32_bf16(kf, qf[u][ks], s_acc[g], 0, 0, 0);
          }

        if (kt == 2 * qtp + u) {               // diagonal tile for this subtile
          const int k0 = kt * 64;
#pragma unroll
          for (int g = 0; g < 4; ++g)
#pragma unroll
            for (int r = 0; r < 4; ++r) {
              int kcol = k0 + g * 16 + quad * 4 + r;
              if (kcol > qrow) s_acc[g][r] = -__builtin_inff();
            }
        }

        // p = exp2(s) (max-free), pack -> Ps
#pragma unroll
        for (int g = 0; g < 4; ++g) {
          bf16x4 pk = { (__bf16)EXP2(s_acc[g][0]), (__bf16)EXP2(s_acc[g][1]),
                        (__bf16)EXP2(s_acc[g][2]), (__bf16)EXP2(s_acc[g][3]) };
          *(bf16x4*)&Ps[wave][u][ln][g * 16 + quad * 4] = pk;
        }
        bf16x8 pf[2];
#pragma unroll
        for (int ks = 0; ks < 2; ++ks)
          pf[ks] = *(const bf16x8*)&Ps[wave][u][ln][ks * 32 + quad * 8];

        // l += P @ ones (row sums land in O-row layout)
        l4[u] = __builtin_amdgcn_mfma_f32_16x16x32_bf16(pf[0], onef, l4[u], 0, 0, 0);
        l4[u] = __builtin_amdgcn_mfma_f32_16x16x32_bf16(pf[1], onef, l4[u], 0, 0, 0);

        // O += P V
#pragma unroll
        for (int g = 0; g < 4; ++g)
#pragma unroll
          for (int ks = 0; ks < 2; ++ks) {
            bf16x8 vf = *(const bf16x8*)&Vt[kslot[g][ks]];
            o[u][g] = __builtin_amdgcn_mfma_f32_16x16x32_bf16(pf[ks], vf, o[u][g], 0, 0, 0);
          }
      }
    }

#pragma unroll
    for (int u = 0; u < 2; ++u) {
      float linv[4];
#pragma unroll
      for (int r = 0; r < 4; ++r) linv[r] = 1.0f / l4[u][r];
#pragma unroll
      for (int g = 0; g < 4; ++g)
#pragma unroll
        for (int r = 0; r < 4; ++r) {
          int orow = q0 + u * 64 + wave * 16 + quad * 4 + r;
          out[((size_t)b_ * Ss + orow) * Ee + h * HD + g * 16 + ln] = o[u][g][r] * linv[r];
        }
    }
    __syncthreads();   // protect LDS before next phase restages
  }
}

extern "C" void kernel_launch(void* const* d_in, const int* in_sizes, int n_in,
                              void* d_out, int out_size, void* d_ws, size_t ws_size,
                              hipStream_t stream) {
  const float* x  = (const float*)d_in[0];
  const float* Wq = (const float*)d_in[1];
  const float* bq = (const float*)d_in[2];
  const float* Wk = (const float*)d_in[3];
  const float* bk = (const float*)d_in[4];
  const float* Wv = (const float*)d_in[5];
  const float* bv = (const float*)d_in[6];
  float* out = (float*)d_out;

  unsigned short* ws  = (unsigned short*)d_ws;
  unsigned short* xb  = ws;                                   // 8388608
  unsigned short* wb  = ws + 8388608;                         // 3 * 1048576
  unsigned short* qkv = ws + 8388608 + 3 * 1048576;           // 3 * 8388608

  cvt_all<<<11264, 256, 0, stream>>>(x, Wq, Wk, Wv, xb, wb);
  qkv_gemm<<<dim3(32, 4, 3), 512, 0, stream>>>(xb, wb, bq, bk, bv, qkv);
  flash_attn<<<512, 256, 0, stream>>>(qkv, out);
}